// Round 17
// baseline (77.608 us; speedup 1.0000x reference)
//
#include <hip/hip_runtime.h>
#include <stdint.h>

#define BB 8
#define NN 2048
#define IND 10
#define QK 32

typedef float f32x4 __attribute__((ext_vector_type(4)));

// Kernel 1: q[b][n][qd] = sum_d s[b,n,d]*Wq[qd,d]; k likewise.
// kt permuted for kernel 2's read: attn thread (wave w, lane i) owns cols
//   {512w + 4i + j : j=0..3} and {512w + 256 + 4i + j : j=0..3}.
// kt float4 index: (b*4+w)*4096 + (ev*8+jc)*64 + i, component c (qd=4ev+c).
__global__ __launch_bounds__(256) void qk_kernel(
    const float* __restrict__ s,
    const float* __restrict__ Wq, const float* __restrict__ Wk,
    float* __restrict__ q_ws, float* __restrict__ kt_ws) {
  int t = blockIdx.x * 256 + threadIdx.x;      // 0 .. B*N*QK-1 (exact)
  int b  = t >> 16;                            // N*QK = 65536
  int n  = (t >> 5) & (NN - 1);
  int qd = t & 31;
  const float* srow = s + (size_t)(b * NN + n) * IND;
  float acq = 0.f, ack = 0.f;
#pragma unroll
  for (int d = 0; d < IND; ++d) {
    float sv = srow[d];
    acq = fmaf(sv, Wq[qd * IND + d], acq);
    ack = fmaf(sv, Wk[qd * IND + d], ack);
  }
  q_ws[(size_t)(b * NN + n) * QK + qd] = acq;
  int w  = n >> 9;                 // wave (512 cols each)
  int m  = n & 511;
  int i  = (m & 255) >> 2;         // lane
  int jc = ((m < 256) ? 0 : 4) + (m & 3);
  int ev = qd >> 2, c = qd & 3;
  kt_ws[(((size_t)(b * 4 + w) * 4096) + (ev * 8 + jc) * 64 + i) * 4 + c] = ack;
}

// Kernel 2: one block = (batch, 8 rows), 256 threads. Thread (w,lane) owns
// cols {512w+4*lane+j} and {512w+256+4*lane+j}, j=0..3, for all 8 rows.
// GEMM: R13's ka/kb k-double-buffer (compiler-scheduled, proven). Epilogue:
// all 16 G float4s loaded via INLINE-ASM global_load_dwordx4 -- volatile asm
// cannot be sunk by MachineSinking (which defeated the C-level prefetch in
// R14/R16, VGPR stuck at 80-100 with ~3 loads in flight => BW capped at
// ~3.4/6.3 TB/s by Little's law). Placed post-GEMM where no compiler
// vmcnt-waits can interleave (all k loads consumed by GEMM end), so manual
// counted waits are correct: vmcnt(8) = "everything older than my newest 8
// retired" => rows 0-3 ready; math on them covers rows 4-7's latency;
// vmcnt(0) => rows 4-7. sched_barrier(0) after each wait per rule #18.
// Peak regs ~150 < 256 cap (launch_bounds 256,2): no spill possible.
__global__ __launch_bounds__(256, 2) void attn_kernel(
    const float* __restrict__ G,
    const float* __restrict__ q_ws, const float* __restrict__ kt_ws,
    float* __restrict__ out) {
  const int tid = threadIdx.x;
  const int b = blockIdx.y;
  const int r0 = blockIdx.x * 8;
  const int w = tid >> 6, lane = tid & 63;

  __shared__ float q_lds[4][256];  // wave-private q tile copies (1 KB/wave)
  __shared__ float red[4][8];

  // ---- wave-private q copy (8 rows x 32 = 256 contiguous floats) ----
  {
    const float* qb = q_ws + ((size_t)b * NN + r0) * QK;
    *(float4*)&q_lds[w][4 * lane] = *(const float4*)&qb[4 * lane];
  }

  // ---- GEMM: acc[r][j] = q[r0+r] . k[col(w,lane,j)] ----
  float acc[8][8];
#pragma unroll
  for (int r = 0; r < 8; ++r)
#pragma unroll
    for (int j = 0; j < 8; ++j) acc[r][j] = 0.f;

  const float4* kt =
      (const float4*)kt_ws + (size_t)(b * 4 + w) * 4096 + lane;

  float4 ka[8], kb[8];
#pragma unroll
  for (int j = 0; j < 8; ++j) ka[j] = kt[j * 64];  // ev=0, lane-coalesced

#pragma unroll
  for (int ev = 0; ev < 8; ++ev) {
    if (ev < 7) {
#pragma unroll
      for (int j = 0; j < 8; ++j) kb[j] = kt[((ev + 1) * 8 + j) * 64];
    }
#pragma unroll
    for (int r = 0; r < 8; ++r) {
      float q4[4];
      *(float4*)q4 = *(const float4*)&q_lds[w][r * 32 + ev * 4];  // broadcast
#pragma unroll
      for (int j = 0; j < 8; ++j) {
        acc[r][j] = fmaf(q4[0], ka[j].x, acc[r][j]);
        acc[r][j] = fmaf(q4[1], ka[j].y, acc[r][j]);
        acc[r][j] = fmaf(q4[2], ka[j].z, acc[r][j]);
        acc[r][j] = fmaf(q4[3], ka[j].w, acc[r][j]);
      }
    }
#pragma unroll
    for (int j = 0; j < 8; ++j) ka[j] = kb[j];  // renamed away by unroll
  }

  // ---- epilogue: 16 asm G loads, all in flight (16 KB/wave) ----
  const float* gb = G + ((size_t)b * NN + r0) * NN + 512 * w + 4 * lane;
  f32x4 g0[8], g1[8];
  {
    const float* p = gb;
#pragma unroll
    for (int r = 0; r < 8; ++r) {
      asm volatile("global_load_dwordx4 %0, %1, off"
                   : "=v"(g0[r])
                   : "v"(p));
      asm volatile("global_load_dwordx4 %0, %1, off offset:1024"
                   : "=v"(g1[r])
                   : "v"(p));
      p += NN;
    }
  }

  float rsum[8];

  // rows 0-3 ready (newest 8 loads = rows 4-7 may still fly)
  asm volatile("s_waitcnt vmcnt(8)" ::: "memory");
  __builtin_amdgcn_sched_barrier(0);
#pragma unroll
  for (int r = 0; r < 4; ++r) {
    float gg[8];
    *(f32x4*)&gg[0] = g0[r];
    *(f32x4*)&gg[4] = g1[r];
    float sum = 0.f;
#pragma unroll
    for (int j = 0; j < 8; ++j) {
      float v = acc[r][j];
      v = v * v * gg[j];
      acc[r][j] = v;
      sum += v;
    }
#pragma unroll
    for (int off = 32; off >= 1; off >>= 1) sum += __shfl_xor(sum, off, 64);
    rsum[r] = sum;
  }

  // rows 4-7 ready
  asm volatile("s_waitcnt vmcnt(0)" ::: "memory");
  __builtin_amdgcn_sched_barrier(0);
#pragma unroll
  for (int r = 4; r < 8; ++r) {
    float gg[8];
    *(f32x4*)&gg[0] = g0[r];
    *(f32x4*)&gg[4] = g1[r];
    float sum = 0.f;
#pragma unroll
    for (int j = 0; j < 8; ++j) {
      float v = acc[r][j];
      v = v * v * gg[j];
      acc[r][j] = v;
      sum += v;
    }
#pragma unroll
    for (int off = 32; off >= 1; off >>= 1) sum += __shfl_xor(sum, off, 64);
    rsum[r] = sum;
  }

  // ---- cross-wave reduce ----
  if ((tid & 63) == 0) {
#pragma unroll
    for (int r = 0; r < 8; ++r) red[w][r] = rsum[r];
  }
  __syncthreads();

  float inv[8];
#pragma unroll
  for (int r = 0; r < 8; ++r) {
    float total = red[0][r] + red[1][r] + red[2][r] + red[3][r];
    inv[r] = 1.0f / (total + 1e-6f);
  }

  // ---- scale + coalesced non-temporal store ----
  float* ob = out + ((size_t)b * NN + r0) * NN + 512 * w + 4 * lane;
#pragma unroll
  for (int r = 0; r < 8; ++r) {
    f32x4 o0, o1;
    o0.x = acc[r][0] * inv[r]; o0.y = acc[r][1] * inv[r];
    o0.z = acc[r][2] * inv[r]; o0.w = acc[r][3] * inv[r];
    o1.x = acc[r][4] * inv[r]; o1.y = acc[r][5] * inv[r];
    o1.z = acc[r][6] * inv[r]; o1.w = acc[r][7] * inv[r];
    __builtin_nontemporal_store(o0, (f32x4*)(ob + (size_t)r * NN));
    __builtin_nontemporal_store(o1, (f32x4*)(ob + (size_t)r * NN + 256));
  }
}

extern "C" void kernel_launch(void* const* d_in, const int* in_sizes, int n_in,
                              void* d_out, int out_size, void* d_ws, size_t ws_size,
                              hipStream_t stream) {
  const float* s  = (const float*)d_in[0];
  const float* G  = (const float*)d_in[1];
  const float* Wq = (const float*)d_in[2];
  const float* Wk = (const float*)d_in[3];
  float* out = (float*)d_out;

  float* q_ws  = (float*)d_ws;                       // B*N*QK floats = 2 MB
  float* kt_ws = q_ws + (size_t)BB * NN * QK;        // another 2 MB

  qk_kernel<<<(BB * NN * QK) / 256, 256, 0, stream>>>(s, Wq, Wk, q_ws, kt_ws);

  dim3 grid(NN / 8, BB);
  attn_kernel<<<grid, 256, 0, stream>>>(G, q_ws, kt_ws, out);
}

// Round 18
// 73.901 us; speedup vs baseline: 1.0502x; 1.0502x over previous
//
#include <hip/hip_runtime.h>
#include <stdint.h>

#define BB 8
#define NN 2048
#define IND 10
#define QK 32

typedef float f32x4 __attribute__((ext_vector_type(4)));

// Kernel 1: q[b][n][qd] = sum_d s[b,n,d]*Wq[qd,d]; k likewise.
// kt permuted for kernel 2's 8-wave x 256-col tile: attn thread (wave w in
// [0,8), lane i) owns cols {256w + 4i + j : j=0..3}. Per ev it loads 4
// float4s, j-th at float4-index ((b*8+w)*8 + ev)*256 + j*64 + i ->
// consecutive lanes hit consecutive float4s (perfect 1KB/instr coalescing).
__global__ __launch_bounds__(256) void qk_kernel(
    const float* __restrict__ s,
    const float* __restrict__ Wq, const float* __restrict__ Wk,
    float* __restrict__ q_ws, float* __restrict__ kt_ws) {
  int t = blockIdx.x * 256 + threadIdx.x;      // 0 .. B*N*QK-1 (exact)
  int b  = t >> 16;                            // N*QK = 65536
  int n  = (t >> 5) & (NN - 1);
  int qd = t & 31;
  const float* srow = s + (size_t)(b * NN + n) * IND;
  float acq = 0.f, ack = 0.f;
#pragma unroll
  for (int d = 0; d < IND; ++d) {
    float sv = srow[d];
    acq = fmaf(sv, Wq[qd * IND + d], acq);
    ack = fmaf(sv, Wk[qd * IND + d], ack);
  }
  q_ws[(size_t)(b * NN + n) * QK + qd] = acq;
  int w  = n >> 8;          // wave (256 cols each)
  int i  = (n >> 2) & 63;   // lane
  int j  = n & 3;           // col within thread's 4
  int ev = qd >> 2, c = qd & 3;
  kt_ws[((((size_t)(b * 8 + w) * 8) + ev) * 256 + j * 64 + i) * 4 + c] = ack;
}

// Kernel 2: one block = (batch, 8 rows), 512 threads = 8 waves. Wave w owns
// cols [256w, 256w+256); thread (w,lane) owns cols 256w+4*lane..+3 for all
// 8 rows. Same traffic as R16 (k L2 537 MB, G 134 MB, out 134 MB) but HALF
// the per-thread state: acc[8][4]=32 regs, G prefetch 32, k-dbuf 32 ->
// peak ~100 VGPR. Per-wave load chains halve; waves/CU double at equal
// VGPR; low pressure lets the allocator keep the G prefetch materialized
// (it sank the 64-reg version in R14/R16, spilled the asm one in R17).
// Wave-private q copies: no barrier before the cross-wave reduce.
__global__ __launch_bounds__(512) void attn_kernel(
    const float* __restrict__ G,
    const float* __restrict__ q_ws, const float* __restrict__ kt_ws,
    float* __restrict__ out) {
  const int tid = threadIdx.x;
  const int b = blockIdx.y;
  const int r0 = blockIdx.x * 8;
  const int w = tid >> 6, lane = tid & 63;

  __shared__ float q_lds[8][256];  // wave-private q tile copies (1 KB/wave)
  __shared__ float red[8][8];

  // ---- wave-private q copy (8 rows x 32 = 256 contiguous floats) ----
  {
    const float* qb = q_ws + ((size_t)b * NN + r0) * QK;
    *(float4*)&q_lds[w][4 * lane] = *(const float4*)&qb[4 * lane];
  }

  // ---- GEMM: acc[r][j] = q[r0+r] . k[col = 256w + 4*lane + j] ----
  float acc[8][4];
#pragma unroll
  for (int r = 0; r < 8; ++r)
#pragma unroll
    for (int j = 0; j < 4; ++j) acc[r][j] = 0.f;

  const float4* kt =
      (const float4*)kt_ws + (size_t)(b * 8 + w) * 2048 + lane;

  float4 ka[4], kb[4];
#pragma unroll
  for (int j = 0; j < 4; ++j) ka[j] = kt[j * 64];  // ev=0, lane-coalesced

#pragma unroll
  for (int ev = 0; ev < 8; ++ev) {
    if (ev < 7) {
#pragma unroll
      for (int j = 0; j < 4; ++j) kb[j] = kt[(ev + 1) * 256 + j * 64];
    }
#pragma unroll
    for (int r = 0; r < 8; ++r) {
      float q4[4];
      *(float4*)q4 = *(const float4*)&q_lds[w][r * 32 + ev * 4];  // broadcast
#pragma unroll
      for (int j = 0; j < 4; ++j) {
        acc[r][j] = fmaf(q4[0], ka[j].x, acc[r][j]);
        acc[r][j] = fmaf(q4[1], ka[j].y, acc[r][j]);
        acc[r][j] = fmaf(q4[2], ka[j].z, acc[r][j]);
        acc[r][j] = fmaf(q4[3], ka[j].w, acc[r][j]);
      }
    }
#pragma unroll
    for (int j = 0; j < 4; ++j) ka[j] = kb[j];  // renamed away by unroll
  }

  // ---- epilogue: prefetch this thread's 8 G float4s, then math ----
  const float* gb = G + ((size_t)b * NN + r0) * NN + 256 * w + 4 * lane;
  float4 g0[8];
#pragma unroll
  for (int r = 0; r < 8; ++r) g0[r] = *(const float4*)(gb + (size_t)r * NN);
  __builtin_amdgcn_sched_barrier(0);  // math stays below the loads

  float rsum[8];
#pragma unroll
  for (int r = 0; r < 8; ++r) {
    float gg[4];
    *(float4*)&gg[0] = g0[r];
    float sum = 0.f;
#pragma unroll
    for (int j = 0; j < 4; ++j) {
      float v = acc[r][j];
      v = v * v * gg[j];
      acc[r][j] = v;
      sum += v;
    }
#pragma unroll
    for (int off = 32; off >= 1; off >>= 1) sum += __shfl_xor(sum, off, 64);
    rsum[r] = sum;
  }

  // ---- cross-wave reduce (8 waves) ----
  if ((tid & 63) == 0) {
#pragma unroll
    for (int r = 0; r < 8; ++r) red[w][r] = rsum[r];
  }
  __syncthreads();

  float inv[8];
#pragma unroll
  for (int r = 0; r < 8; ++r) {
    float total = 0.f;
#pragma unroll
    for (int w2 = 0; w2 < 8; ++w2) total += red[w2][r];  // uniform broadcast
    inv[r] = 1.0f / (total + 1e-6f);
  }

  // ---- scale + coalesced non-temporal store ----
  float* ob = out + ((size_t)b * NN + r0) * NN + 256 * w + 4 * lane;
#pragma unroll
  for (int r = 0; r < 8; ++r) {
    f32x4 o;
    o.x = acc[r][0] * inv[r];
    o.y = acc[r][1] * inv[r];
    o.z = acc[r][2] * inv[r];
    o.w = acc[r][3] * inv[r];
    __builtin_nontemporal_store(o, (f32x4*)(ob + (size_t)r * NN));
  }
}

extern "C" void kernel_launch(void* const* d_in, const int* in_sizes, int n_in,
                              void* d_out, int out_size, void* d_ws, size_t ws_size,
                              hipStream_t stream) {
  const float* s  = (const float*)d_in[0];
  const float* G  = (const float*)d_in[1];
  const float* Wq = (const float*)d_in[2];
  const float* Wk = (const float*)d_in[3];
  float* out = (float*)d_out;

  float* q_ws  = (float*)d_ws;                       // B*N*QK floats = 2 MB
  float* kt_ws = q_ws + (size_t)BB * NN * QK;        // another 2 MB

  qk_kernel<<<(BB * NN * QK) / 256, 256, 0, stream>>>(s, Wq, Wk, q_ws, kt_ws);

  dim3 grid(NN / 8, BB);
  attn_kernel<<<grid, 512, 0, stream>>>(G, q_ws, kt_ws, out);
}

// Round 19
// 66.110 us; speedup vs baseline: 1.1739x; 1.1179x over previous
//
#include <hip/hip_runtime.h>
#include <stdint.h>

#define BB 8
#define NN 2048
#define IND 10
#define QK 32

typedef float f32x4 __attribute__((ext_vector_type(4)));

// Kernel 1: q[b][n][qd] = sum_d s[b,n,d]*Wq[qd,d]; k likewise.
// kt permuted for kernel 2's read: attn thread (wave w, lane i) owns cols
//   {512w + 4i + j : j=0..3} and {512w + 256 + 4i + j : j=0..3}.
// kt float4 index: (b*4+w)*4096 + (ev*8+jc)*64 + i, component c (qd=4ev+c).
__global__ __launch_bounds__(256) void qk_kernel(
    const float* __restrict__ s,
    const float* __restrict__ Wq, const float* __restrict__ Wk,
    float* __restrict__ q_ws, float* __restrict__ kt_ws) {
  int t = blockIdx.x * 256 + threadIdx.x;      // 0 .. B*N*QK-1 (exact)
  int b  = t >> 16;                            // N*QK = 65536
  int n  = (t >> 5) & (NN - 1);
  int qd = t & 31;
  const float* srow = s + (size_t)(b * NN + n) * IND;
  float acq = 0.f, ack = 0.f;
#pragma unroll
  for (int d = 0; d < IND; ++d) {
    float sv = srow[d];
    acq = fmaf(sv, Wq[qd * IND + d], acq);
    ack = fmaf(sv, Wk[qd * IND + d], ack);
  }
  q_ws[(size_t)(b * NN + n) * QK + qd] = acq;
  int w  = n >> 9;                 // wave (512 cols each)
  int m  = n & 511;
  int i  = (m & 255) >> 2;         // lane
  int jc = ((m < 256) ? 0 : 4) + (m & 3);
  int ev = qd >> 2, c = qd & 3;
  kt_ws[(((size_t)(b * 4 + w) * 4096) + (ev * 8 + jc) * 64 + i) * 4 + c] = ack;
}

// Kernel 2: one block = (batch, 8 rows), 256 threads. Thread (w,lane) owns
// cols {512w+4*lane+j} and {512w+256+4*lane+j}, j=0..3, for all 8 rows.
// GEMM: R13's ka/kb k-double-buffer. Epilogue: 16 G float4 loads grouped
// BEFORE the math via sched_group_barrier (T19) -- the one mechanism not yet
// tried: the MachineScheduler honors it, the compiler keeps ownership of
// waitcnt insertion (no manual vmcnt fragility like R17's asm pins), and RA
// can split live ranges instead of spilling. Peak regs if honored ~150 <
// 256 cap (launch_bounds 256,2).
__global__ __launch_bounds__(256, 2) void attn_kernel(
    const float* __restrict__ G,
    const float* __restrict__ q_ws, const float* __restrict__ kt_ws,
    float* __restrict__ out) {
  const int tid = threadIdx.x;
  const int b = blockIdx.y;
  const int r0 = blockIdx.x * 8;
  const int w = tid >> 6, lane = tid & 63;

  __shared__ float q_lds[4][256];  // wave-private q tile copies (1 KB/wave)
  __shared__ float red[4][8];

  // ---- wave-private q copy (8 rows x 32 = 256 contiguous floats) ----
  {
    const float* qb = q_ws + ((size_t)b * NN + r0) * QK;
    *(float4*)&q_lds[w][4 * lane] = *(const float4*)&qb[4 * lane];
  }

  // ---- GEMM: acc[r][j] = q[r0+r] . k[col(w,lane,j)] ----
  float acc[8][8];
#pragma unroll
  for (int r = 0; r < 8; ++r)
#pragma unroll
    for (int j = 0; j < 8; ++j) acc[r][j] = 0.f;

  const float4* kt =
      (const float4*)kt_ws + (size_t)(b * 4 + w) * 4096 + lane;

  float4 ka[8], kb[8];
#pragma unroll
  for (int j = 0; j < 8; ++j) ka[j] = kt[j * 64];  // ev=0, lane-coalesced

#pragma unroll
  for (int ev = 0; ev < 8; ++ev) {
    if (ev < 7) {
#pragma unroll
      for (int j = 0; j < 8; ++j) kb[j] = kt[((ev + 1) * 8 + j) * 64];
    }
#pragma unroll
    for (int r = 0; r < 8; ++r) {
      float q4[4];
      *(float4*)q4 = *(const float4*)&q_lds[w][r * 32 + ev * 4];  // broadcast
#pragma unroll
      for (int j = 0; j < 8; ++j) {
        acc[r][j] = fmaf(q4[0], ka[j].x, acc[r][j]);
        acc[r][j] = fmaf(q4[1], ka[j].y, acc[r][j]);
        acc[r][j] = fmaf(q4[2], ka[j].z, acc[r][j]);
        acc[r][j] = fmaf(q4[3], ka[j].w, acc[r][j]);
      }
    }
#pragma unroll
    for (int j = 0; j < 8; ++j) ka[j] = kb[j];  // renamed away by unroll
  }

  // ---- epilogue: load ALL 16 G float4s; SGB groups them before the math
  //      (loads are after the last k-load in program order, so the
  //      compiler's k vmcnt-waits never count them) ----
  const float* gb = G + ((size_t)b * NN + r0) * NN + 512 * w + 4 * lane;
  float4 g0[8], g1[8];
#pragma unroll
  for (int r = 0; r < 8; ++r) {
    g0[r] = *(const float4*)(gb + (size_t)r * NN);
    g1[r] = *(const float4*)(gb + (size_t)r * NN + 256);
  }
  // schedule: 16 VMEM reads first, then the VALU math block
  __builtin_amdgcn_sched_group_barrier(0x20 /*VMEM_READ*/, 16, 0);
  __builtin_amdgcn_sched_group_barrier(0x2 /*VALU*/, 256, 0);

  float rsum[8];
#pragma unroll
  for (int r = 0; r < 8; ++r) {
    float gg[8];
    *(float4*)&gg[0] = g0[r];
    *(float4*)&gg[4] = g1[r];
    float sum = 0.f;
#pragma unroll
    for (int j = 0; j < 8; ++j) {
      float v = acc[r][j];
      v = v * v * gg[j];
      acc[r][j] = v;
      sum += v;
    }
#pragma unroll
    for (int off = 32; off >= 1; off >>= 1) sum += __shfl_xor(sum, off, 64);
    rsum[r] = sum;
  }

  // ---- cross-wave reduce ----
  if ((tid & 63) == 0) {
#pragma unroll
    for (int r = 0; r < 8; ++r) red[w][r] = rsum[r];
  }
  __syncthreads();

  float inv[8];
#pragma unroll
  for (int r = 0; r < 8; ++r) {
    float total = red[0][r] + red[1][r] + red[2][r] + red[3][r];
    inv[r] = 1.0f / (total + 1e-6f);
  }

  // ---- scale + coalesced non-temporal store ----
  float* ob = out + ((size_t)b * NN + r0) * NN + 512 * w + 4 * lane;
#pragma unroll
  for (int r = 0; r < 8; ++r) {
    f32x4 o0, o1;
    o0.x = acc[r][0] * inv[r]; o0.y = acc[r][1] * inv[r];
    o0.z = acc[r][2] * inv[r]; o0.w = acc[r][3] * inv[r];
    o1.x = acc[r][4] * inv[r]; o1.y = acc[r][5] * inv[r];
    o1.z = acc[r][6] * inv[r]; o1.w = acc[r][7] * inv[r];
    __builtin_nontemporal_store(o0, (f32x4*)(ob + (size_t)r * NN));
    __builtin_nontemporal_store(o1, (f32x4*)(ob + (size_t)r * NN + 256));
  }
}

extern "C" void kernel_launch(void* const* d_in, const int* in_sizes, int n_in,
                              void* d_out, int out_size, void* d_ws, size_t ws_size,
                              hipStream_t stream) {
  const float* s  = (const float*)d_in[0];
  const float* G  = (const float*)d_in[1];
  const float* Wq = (const float*)d_in[2];
  const float* Wk = (const float*)d_in[3];
  float* out = (float*)d_out;

  float* q_ws  = (float*)d_ws;                       // B*N*QK floats = 2 MB
  float* kt_ws = q_ws + (size_t)BB * NN * QK;        // another 2 MB

  qk_kernel<<<(BB * NN * QK) / 256, 256, 0, stream>>>(s, Wq, Wk, q_ws, kt_ws);

  dim3 grid(NN / 8, BB);
  attn_kernel<<<grid, 256, 0, stream>>>(G, q_ws, kt_ws, out);
}